// Round 16
// baseline (3818.739 us; speedup 1.0000x reference)
//
#include <hip/hip_runtime.h>
#include <math.h>

#define DIM  1024
#define SEQ  64
#define HDIM 256
#define NBLK 64
#define TPB  1024
#define SLOT_STRIDE 32      // 32 u32 = 128 B
#define SENTU 0xFFC00ABCu   // NaN sentinel: computations never produce this pattern

// ---------------- wave / block reduction helpers ----------------
__device__ __forceinline__ float wsum(float v){
  v += __shfl_xor(v, 32, 64); v += __shfl_xor(v, 16, 64); v += __shfl_xor(v, 8, 64);
  v += __shfl_xor(v, 4, 64);  v += __shfl_xor(v, 2, 64);  v += __shfl_xor(v, 1, 64);
  return v;
}
__device__ __forceinline__ float wmax(float v){
  v = fmaxf(v, __shfl_xor(v, 32, 64)); v = fmaxf(v, __shfl_xor(v, 16, 64));
  v = fmaxf(v, __shfl_xor(v, 8, 64));  v = fmaxf(v, __shfl_xor(v, 4, 64));
  v = fmaxf(v, __shfl_xor(v, 2, 64));  v = fmaxf(v, __shfl_xor(v, 1, 64));
  return v;
}
// block-wide 2-value reduce over 16 waves
__device__ __forceinline__ float2 breduce2(float va, float vb, float* red){
  int tid = threadIdx.x;
  va = wsum(va); vb = wsum(vb);
  if ((tid & 63) == 0){ red[(tid >> 6) * 2] = va; red[(tid >> 6) * 2 + 1] = vb; }
  __syncthreads();
  float ra = 0.f, rb = 0.f;
  #pragma unroll
  for (int w = 0; w < 16; ++w){ ra += red[2 * w]; rb += red[2 * w + 1]; }
  __syncthreads();
  return make_float2(ra, rb);
}

// ---------------- device-coherent primitives (R8-proven) ----------------
__device__ __forceinline__ float ldc(const float* p){
  return __hip_atomic_load(p, __ATOMIC_RELAXED, __HIP_MEMORY_SCOPE_AGENT);
}
__device__ __forceinline__ void stc(float* p, float v){
  __hip_atomic_store(p, v, __ATOMIC_RELAXED, __HIP_MEMORY_SCOPE_AGENT);
}
__device__ __forceinline__ void sta(unsigned* p, unsigned v){
  __hip_atomic_store(p, v, __ATOMIC_RELAXED, __HIP_MEMORY_SCOPE_AGENT);
}
// sentinel poll: value arrives with its own validity (one-phase handoff)
__device__ __forceinline__ float plc(const float* p){
  float v = ldc(p);
  unsigned s = 0;
  while (__float_as_uint(v) == SENTU){ v = ldc(p); if (++s > 200000000u) break; }
  return v;
}
__device__ __forceinline__ void spin_ge(unsigned* p, unsigned ep){
  unsigned spins = 0;
  while (__hip_atomic_load(p, __ATOMIC_RELAXED, __HIP_MEMORY_SCOPE_AGENT) < ep){
    if (++spins > 100000000u) break;
  }
}
// flat barrier (R8-proven), prologue stages only
__device__ __forceinline__ void gsync(unsigned* slots, unsigned ep, int bid, int tid){
  asm volatile("s_waitcnt vmcnt(0)" ::: "memory");
  __syncthreads();
  if (tid == 0) sta(&slots[bid * SLOT_STRIDE], ep);
  if (tid < NBLK) spin_ge(&slots[tid * SLOT_STRIDE], ep);
  __syncthreads();
  asm volatile("" ::: "memory");
}

// ---------------- prologue matmul: 64x64 tile, 4x4 per thread ----------------
__global__ void mm1024(const float* __restrict__ A0, const float* __restrict__ B,
                       float* __restrict__ C0, size_t Astride, size_t Cstride){
  const float* A = A0 + (size_t)blockIdx.z * Astride;
  float* C = C0 + (size_t)blockIdx.z * Cstride;
  __shared__ float As[16][65];
  __shared__ float Bs[16][65];
  int ta = blockIdx.y * 64, tb = blockIdx.x * 64;
  int tx = threadIdx.x & 15, ty = threadIdx.x >> 4;
  float acc[4][4] = {};
  for (int k0 = 0; k0 < 1024; k0 += 16){
    #pragma unroll
    for (int j = 0; j < 4; ++j)
      As[tx][ty * 4 + j] = A[(size_t)(ta + ty * 4 + j) * 1024 + k0 + tx];
    {
      const float4 bv = *(const float4*)&B[(size_t)(k0 + ty) * 1024 + tb + tx * 4];
      Bs[ty][tx * 4]     = bv.x; Bs[ty][tx * 4 + 1] = bv.y;
      Bs[ty][tx * 4 + 2] = bv.z; Bs[ty][tx * 4 + 3] = bv.w;
    }
    __syncthreads();
    #pragma unroll
    for (int kk = 0; kk < 16; ++kk){
      float av[4], bv[4];
      #pragma unroll
      for (int m = 0; m < 4; ++m) av[m] = As[kk][ty * 4 + m];
      #pragma unroll
      for (int n = 0; n < 4; ++n) bv[n] = Bs[kk][tx * 4 + n];
      #pragma unroll
      for (int m = 0; m < 4; ++m)
        #pragma unroll
        for (int n = 0; n < 4; ++n) acc[m][n] = fmaf(av[m], bv[n], acc[m][n]);
    }
    __syncthreads();
  }
  #pragma unroll
  for (int m = 0; m < 4; ++m){
    float4 ov = { acc[m][0], acc[m][1], acc[m][2], acc[m][3] };
    *(float4*)&C[(size_t)(ta + ty * 4 + m) * 1024 + tb + tx * 4] = ov;
  }
}

// sentinel-fill the write-once dataflow arrays (runs every launch; re-poison safe)
__global__ void sentinit(unsigned* p, size_t n){
  size_t idx = (size_t)blockIdx.x * 256 + threadIdx.x;
  for (size_t k = idx; k < n; k += (size_t)gridDim.x * 256) p[k] = SENTU;
}

// ---------------- the persistent autoregressive decode ----------------
struct CoopArgs {
  const float *hs, *hid_w, *hid_b;
  const float *sa_in_w, *sa_in_b, *sa_out_w, *sa_out_b;
  const float *ca_in_w, *ca_in_b, *ca_out_w, *ca_out_b;
  const float *ln1_g, *ln1_b, *ln2_g, *ln2_b, *ln3_g, *ln3_b;
  const float *ff1_w, *ff1_b, *ff2_w, *ff2_b;
  const float *vr_w, *vr_b, *vm_w, *vm_b, *obj_w;
  const float *Cm, *WqF, *WkF, *WvF;
  float *mem, *vtmp, *cac;
  float *kc, *qv, *vcB, *uB, *hbB, *wB, *sB;   // write-once dataflow arrays
  float *peT, *stylev, *cbvec, *wqpeT, *wkpeT, *wvpeT;
  float *out;
  unsigned *bar;
};

__global__ void __launch_bounds__(1024, 1) decode_loop(CoopArgs a){
  const int tid = threadIdx.x, bid = blockIdx.x;
  const int wave = tid >> 6, lane = tid & 63;
  const int gw = bid * 16 + wave;           // global wave id / row, 0..1023
  __shared__ float smA[2048];
  __shared__ float smB[1024];
  __shared__ float smC[256];
  __shared__ float scp[256];
  __shared__ float red[32];
  unsigned bep = 0;
  const float NLOG = -9.210340371976184f / 1024.0f;   // -ln(10000)/D

  // ======== P1: mem rows; pe table; style vector ========
  {
    float pw[16];
    const float* pr = a.hid_w + (size_t)gw * DIM;
    #pragma unroll
    for (int k = 0; k < 16; ++k) pw[k] = pr[lane + 64 * k];
    float bias = a.hid_b[gw];
    for (int t = 0; t < 64; ++t){
      const float* xr = a.hs + (size_t)t * DIM;
      float acc = 0.f;
      #pragma unroll
      for (int k = 0; k < 16; ++k) acc = fmaf(pw[k], xr[lane + 64 * k], acc);
      acc = wsum(acc);
      if (lane == 0) stc(a.mem + (size_t)t * DIM + gw, acc + bias);
    }
    if (bid < 30){
      int p = bid;
      float dv = __expf((float)(2 * (tid >> 1)) * NLOG);
      float arg = (float)p * dv;
      stc(a.peT + (size_t)p * DIM + tid, (tid & 1) ? cosf(arg) : sinf(arg));
    } else if (bid == 30){
      stc(a.stylev + tid, a.obj_w[(size_t)tid * 80]);
    }
  }
  ++bep; gsync(a.bar, bep, bid, tid);

  // ======== P2: vtmp rows; cb vector ========
  float cbv;
  {
    const float* pv = a.vm_w + (size_t)gw * DIM;
    float acc = 0.f;
    #pragma unroll
    for (int k = 0; k < 16; ++k) acc = fmaf(pv[lane + 64 * k], a.vr_b[lane + 64 * k], acc);
    acc = wsum(acc);
    cbv = acc + a.vm_b[gw] + ldc(a.stylev + gw);
    if (lane == 0) stc(a.cbvec + gw, cbv);
  }
  {
    float pw[16];
    const float* pr = a.ca_in_w + (size_t)(2 * DIM + gw) * DIM;
    #pragma unroll
    for (int k = 0; k < 16; ++k) pw[k] = pr[lane + 64 * k];
    float bias = a.ca_in_b[2 * DIM + gw];
    for (int t = 0; t < 64; ++t){
      smA[tid] = ldc(a.mem + (size_t)t * DIM + tid);
      __syncthreads();
      float acc = 0.f;
      #pragma unroll
      for (int k = 0; k < 16; ++k) acc = fmaf(pw[k], smA[lane + 64 * k], acc);
      acc = wsum(acc);
      if (lane == 0) stc(a.vtmp + (size_t)t * DIM + gw, acc + bias);
      __syncthreads();
    }
  }
  ++bep; gsync(a.bar, bep, bid, tid);

  // ======== P3: cac rows ========
  {
    float pw[16];
    const float* pr = a.ca_out_w + (size_t)gw * DIM;
    #pragma unroll
    for (int k = 0; k < 16; ++k) pw[k] = pr[lane + 64 * k];
    float bias = a.ca_out_b[gw];
    for (int t = 0; t < 64; ++t){
      smA[tid] = ldc(a.vtmp + (size_t)t * DIM + tid);
      __syncthreads();
      float acc = 0.f;
      #pragma unroll
      for (int k = 0; k < 16; ++k) acc = fmaf(pw[k], smA[lane + 64 * k], acc);
      acc = wsum(acc);
      if (lane == 0) stc(a.cac + (size_t)t * DIM + gw, acc + bias);
      __syncthreads();
    }
  }
  ++bep; gsync(a.bar, bep, bid, tid);

  // ======== PB: per-row QKV constants (W.cb, W.style, W.pe[p]); publish i=0 q/k/v ========
  float aqcb, akcb, avcb;
  {
    float wqr[16], wkr[16], wvr[16];
    const float* pq = a.sa_in_w + (size_t)gw * DIM;
    const float* pk = a.sa_in_w + (size_t)(DIM + gw) * DIM;
    const float* pv = a.sa_in_w + (size_t)(2 * DIM + gw) * DIM;
    #pragma unroll
    for (int k = 0; k < 16; ++k){
      int d = lane + 64 * k;
      wqr[k] = pq[d]; wkr[k] = pk[d]; wvr[k] = pv[d];
    }
    const float b_q = a.sa_in_b[gw];
    const float b_k = a.sa_in_b[DIM + gw];
    const float b_v = a.sa_in_b[2 * DIM + gw];
    float dq = 0.f, dk = 0.f, dv = 0.f, sq = 0.f, sk = 0.f, sv = 0.f;
    #pragma unroll
    for (int k = 0; k < 16; ++k){
      float xc = ldc(a.cbvec + lane + 64 * k);
      float xs = ldc(a.stylev + lane + 64 * k);
      dq = fmaf(wqr[k], xc, dq); dk = fmaf(wkr[k], xc, dk); dv = fmaf(wvr[k], xc, dv);
      sq = fmaf(wqr[k], xs, sq); sk = fmaf(wkr[k], xs, sk); sv = fmaf(wvr[k], xs, sv);
    }
    aqcb = wsum(dq) + b_q; akcb = wsum(dk) + b_k; avcb = wsum(dv) + b_v;
    sq = wsum(sq); sk = wsum(sk); sv = wsum(sv);
    float pq0 = 0.f, pk0 = 0.f, pv0 = 0.f;
    for (int p = 0; p < 30; ++p){
      const float* pp = a.peT + (size_t)p * DIM;
      float tq = 0.f, tk = 0.f, tv = 0.f;
      #pragma unroll
      for (int k = 0; k < 16; ++k){
        float x = ldc(pp + lane + 64 * k);
        tq = fmaf(wqr[k], x, tq); tk = fmaf(wkr[k], x, tk); tv = fmaf(wvr[k], x, tv);
      }
      tq = wsum(tq); tk = wsum(tk); tv = wsum(tv);
      if (lane == 0){
        stc(a.wqpeT + (size_t)p * DIM + gw, tq);
        stc(a.wkpeT + (size_t)p * DIM + gw, tk);
        stc(a.wvpeT + (size_t)p * DIM + gw, tv);
      }
      if (p == 0){ pq0 = tq; pk0 = tk; pv0 = tv; }
    }
    if (lane == 0){
      stc(a.qv + gw, sq + pq0 + b_q);
      stc(a.kc + gw, sk + pk0 + b_k);
      stc(a.vcB + gw, sv + pv0 + b_v);
    }
  }
  ++bep; gsync(a.bar, bep, bid, tid);   // wqpeT tables must be globally visible

  // ---- preload folded/main weight rows (128 floats/thread)
  float fq[16], fk[16], fv[16], wo[16], f1a[16], f1b[16], f2[32];
  {
    const float* pq = a.WqF + (size_t)gw * DIM;
    const float* pk = a.WkF + (size_t)gw * DIM;
    const float* pv = a.WvF + (size_t)gw * DIM;
    const float* po = a.sa_out_w + (size_t)gw * DIM;
    const float* p1a = a.ff1_w + (size_t)(2 * gw) * DIM;
    const float* p1b = a.ff1_w + (size_t)(2 * gw + 1) * DIM;
    const float* p2 = a.ff2_w + (size_t)gw * 2048;
    #pragma unroll
    for (int k = 0; k < 16; ++k){
      int d = lane + 64 * k;
      fq[k] = pq[d]; fk[k] = pk[d]; fv[k] = pv[d]; wo[k] = po[d];
      f1a[k] = p1a[d]; f1b[k] = p1b[d];
    }
    #pragma unroll
    for (int k = 0; k < 32; ++k) f2[k] = p2[lane + 64 * k];
  }
  const float b_o  = a.sa_out_b[gw];
  const float b_1a = a.ff1_b[2 * gw];
  const float b_1b = a.ff1_b[2 * gw + 1];
  const float b_2  = a.ff2_b[gw];
  const float b_vr = a.vr_b[gw];

  float c0 = 0.f, c1 = 0.f, c2 = 0.f, c3 = 0.f;
  const bool is_score = (bid < 4);          // head = bid; 16 waves x 4 j's each
  const float sc_slope = 1.0f / (float)(4 << (2 * bid));

  float xres = a.obj_w[(size_t)gw * 80] + ldc(a.peT + gw);
  float vrr[16], cmr[16];

  for (int i = 0; i < SEQ; ++i){
    // ---- MS2: attention -> u
    {
      smB[tid] = plc(a.vcB + (size_t)i * DIM + tid);                 // V row
      if (is_score && tid < 256) smC[tid] = plc(a.qv + (size_t)i * DIM + bid * HDIM + tid);
      __syncthreads();
      // c-update from V row
      float p0 = 0.f, p1 = 0.f, p2 = 0.f, p3 = 0.f;
      #pragma unroll
      for (int k = 0; k < 4; ++k){
        p0 = fmaf(wo[k],      smB[lane + 64 * k],        p0);
        p1 = fmaf(wo[k + 4],  smB[lane + 64 * (k + 4)],  p1);
        p2 = fmaf(wo[k + 8],  smB[lane + 64 * (k + 8)],  p2);
        p3 = fmaf(wo[k + 12], smB[lane + 64 * (k + 12)], p3);
      }
      p0 = wsum(p0); p1 = wsum(p1); p2 = wsum(p2); p3 = wsum(p3);
      if (lane == i){ c0 = p0; c1 = p1; c2 = p2; c3 = p3; }
      // scores (blocks 0..3; head = bid; wave covers j = wave*4..+3)
      if (is_score){
        #pragma unroll
        for (int jj = 0; jj < 4; ++jj){
          int j = wave * 4 + jj;
          if (j <= i){
            const float* kr = a.kc + (size_t)j * DIM + bid * HDIM + lane;
            float acc = 0.f;
            #pragma unroll
            for (int m = 0; m < 4; ++m) acc = fmaf(smC[m * 64 + lane], plc(kr + m * 64), acc);
            acc = wsum(acc);
            if (lane == 0)
              stc(a.sB + (size_t)i * 256 + bid * 64 + j,
                  acc * 0.0625f - sc_slope * (float)((i - j) / 30));
          }
        }
      }
      // all blocks: stage scores (mask j>i), softmax by waves 0..3
      if (tid < 256){
        int j = tid & 63;
        scp[tid] = (j <= i) ? plc(a.sB + (size_t)i * 256 + tid) : -3.0e38f;
      }
      __syncthreads();
      if (wave < 4){
        float sv = scp[wave * 64 + lane];
        float mx = wmax(sv);
        float p = (lane <= i) ? __expf(sv - mx) : 0.f;
        float sum = wsum(p);
        scp[wave * 64 + lane] = p / sum;
      }
      __syncthreads();
      float t = scp[lane] * c0 + scp[64 + lane] * c1 + scp[128 + lane] * c2 + scp[192 + lane] * c3;
      t = wsum(t);
      if (lane == 0) stc(a.uB + (size_t)i * DIM + gw, xres + t + b_o);
      __syncthreads();
    }

    // ---- MS3: ln1 -> +cac -> ln2 ; ff1 -> hb
    float x2v;
    {
      float cr = ldc(a.cac + (size_t)i * DIM + tid);
      float xv = plc(a.uB + (size_t)i * DIM + tid);
      float2 r = breduce2(xv, xv * xv, red);
      float mean = r.x * (1.f / 1024.f);
      float var  = r.y * (1.f / 1024.f) - mean * mean;
      float rs = 1.f / sqrtf(var + 1e-5f);
      float x1 = (xv - mean) * rs * a.ln1_g[tid] + a.ln1_b[tid];
      float tv = x1 + cr;
      float2 r2v = breduce2(tv, tv * tv, red);
      float mean2 = r2v.x * (1.f / 1024.f);
      float var2  = r2v.y * (1.f / 1024.f) - mean2 * mean2;
      float rs2 = 1.f / sqrtf(var2 + 1e-5f);
      smA[tid] = (tv - mean2) * rs2 * a.ln2_g[tid] + a.ln2_b[tid];
      __syncthreads();
      x2v = smA[gw];
      float acc0 = 0.f, acc1 = 0.f;
      #pragma unroll
      for (int k = 0; k < 16; ++k){
        float x = smA[lane + 64 * k];
        acc0 = fmaf(f1a[k], x, acc0);
        acc1 = fmaf(f1b[k], x, acc1);
      }
      acc0 = wsum(acc0); acc1 = wsum(acc1);
      if (lane == 0){
        stc(a.hbB + (size_t)i * 2048 + 2 * gw,     fmaxf(acc0 + b_1a, 0.f));
        stc(a.hbB + (size_t)i * 2048 + 2 * gw + 1, fmaxf(acc1 + b_1b, 0.f));
      }
      __syncthreads();
    }

    // ---- MS4: ff2 -> w ; prefetch vr_w/Cm rows
    {
      const float* pr = a.vr_w + (size_t)gw * DIM;
      const float* pc = a.Cm + (size_t)gw * DIM;
      #pragma unroll
      for (int k = 0; k < 16; ++k){ vrr[k] = pr[lane + 64 * k]; cmr[k] = pc[lane + 64 * k]; }
      smA[tid] = plc(a.hbB + (size_t)i * 2048 + tid);
      smA[1024 + tid] = plc(a.hbB + (size_t)i * 2048 + 1024 + tid);
      __syncthreads();
      float acc = 0.f;
      #pragma unroll
      for (int k = 0; k < 32; ++k) acc = fmaf(f2[k], smA[lane + 64 * k], acc);
      acc = wsum(acc);
      if (lane == 0) stc(a.wB + (size_t)i * DIM + gw, x2v + acc + b_2);
      __syncthreads();
    }

    // ---- MS1': ln3 -> y ; out row i ; folded QKV + residual for i+1
    {
      float wvv = plc(a.wB + (size_t)i * DIM + tid);
      float2 r = breduce2(wvv, wvv * wvv, red);
      float mean = r.x * (1.f / 1024.f);
      float var  = r.y * (1.f / 1024.f) - mean * mean;
      float rs = 1.f / sqrtf(var + 1e-5f);
      smA[tid] = (wvv - mean) * rs * a.ln3_g[tid] + a.ln3_b[tid];
      __syncthreads();
      float ar = 0.f, ac = 0.f, aqn = 0.f, akn = 0.f, avn = 0.f;
      #pragma unroll
      for (int k = 0; k < 16; ++k){
        float x = smA[lane + 64 * k];
        ar  = fmaf(vrr[k], x, ar);
        ac  = fmaf(cmr[k], x, ac);
        aqn = fmaf(fq[k], x, aqn);
        akn = fmaf(fk[k], x, akn);
        avn = fmaf(fv[k], x, avn);
      }
      ar = wsum(ar); ac = wsum(ac);
      aqn = wsum(aqn); akn = wsum(akn); avn = wsum(avn);
      if (lane == 0) a.out[(size_t)i * DIM + gw] = ar + b_vr;
      if (i < SEQ - 1){
        int pn = (i + 1) % 30;
        if (lane == 0){
          float tq = ldc(a.wqpeT + (size_t)pn * DIM + gw);
          float tk = ldc(a.wkpeT + (size_t)pn * DIM + gw);
          float tv = ldc(a.wvpeT + (size_t)pn * DIM + gw);
          stc(a.qv + (size_t)(i + 1) * DIM + gw, aqn + aqcb + tq);
          stc(a.kc + (size_t)(i + 1) * DIM + gw, akn + akcb + tk);
          stc(a.vcB + (size_t)(i + 1) * DIM + gw, avn + avcb + tv);
        }
        xres = ac + cbv + ldc(a.peT + (size_t)pn * DIM + gw);
      }
      __syncthreads();
    }
  }
}

// ---------------- host launcher ----------------
extern "C" void kernel_launch(void* const* d_in, const int* in_sizes, int n_in,
                              void* d_out, int out_size, void* d_ws, size_t ws_size,
                              hipStream_t stream){
  const float* hs       = (const float*)d_in[0];
  const float* hid_w    = (const float*)d_in[1];
  const float* hid_b    = (const float*)d_in[2];
  const float* obj_w    = (const float*)d_in[3];
  const float* sa_in_w  = (const float*)d_in[4];
  const float* sa_in_b  = (const float*)d_in[5];
  const float* sa_out_w = (const float*)d_in[6];
  const float* sa_out_b = (const float*)d_in[7];
  const float* ca_in_w  = (const float*)d_in[8];
  const float* ca_in_b  = (const float*)d_in[9];
  const float* ca_out_w = (const float*)d_in[10];
  const float* ca_out_b = (const float*)d_in[11];
  const float* ln1_g    = (const float*)d_in[12];
  const float* ln1_b    = (const float*)d_in[13];
  const float* ln2_g    = (const float*)d_in[14];
  const float* ln2_b    = (const float*)d_in[15];
  const float* ln3_g    = (const float*)d_in[16];
  const float* ln3_b    = (const float*)d_in[17];
  const float* ff1_w    = (const float*)d_in[18];
  const float* ff1_b    = (const float*)d_in[19];
  const float* ff2_w    = (const float*)d_in[20];
  const float* ff2_b    = (const float*)d_in[21];
  const float* vr_w     = (const float*)d_in[22];
  const float* vr_b     = (const float*)d_in[23];
  const float* vm_w     = (const float*)d_in[24];
  const float* vm_b     = (const float*)d_in[25];

  float* ws = (float*)d_ws;
  float* mem    = ws;                 // 65536
  float* vtmp   = ws + 65536;         // 65536
  float* cac    = ws + 131072;        // 65536
  // ---- write-once dataflow region (sentinel-initialized each launch) ----
  float* kc     = ws + 196608;        // 65536  [64][1024]
  float* qv     = ws + 262144;        // 65536
  float* vcB    = ws + 327680;        // 65536
  float* uB     = ws + 393216;        // 65536
  float* hbB    = ws + 458752;        // 131072 [64][2048]
  float* wB     = ws + 589824;        // 65536
  float* sB     = ws + 655360;        // 16384  [64][256]
  // ---- constants / tables ----
  float* peT    = ws + 671744;        // 30720
  float* stylev = ws + 702464;        // 1024
  float* cbvec  = ws + 703488;        // 1024
  float* wqpeT  = ws + 704512;        // 30720
  float* wkpeT  = ws + 735232;        // 30720
  float* wvpeT  = ws + 765952;        // 30720
  unsigned* bar = (unsigned*)(ws + 796672);   // 64 lines x 128B = 8KB
  float* Cm     = ws + 804864;        // 1048576
  float* WqF    = ws + 1853440;       // 1048576
  float* WkF    = ws + 2902016;       // 1048576
  float* WvF    = ws + 3950592;       // 1048576 -> end 4999168 floats (~20MB)

  hipMemsetAsync((void*)bar, 0, NBLK * SLOT_STRIDE * 4, stream);
  sentinit<<<512, 256, 0, stream>>>((unsigned*)kc, 475136);   // kc..sB

  mm1024<<<dim3(16, 16, 1), 256, 0, stream>>>(vm_w, vr_w, Cm, 0, 0);
  mm1024<<<dim3(16, 16, 3), 256, 0, stream>>>(sa_in_w, Cm, WqF,
                                              (size_t)1024 * 1024, (size_t)1024 * 1024);

  CoopArgs A;
  A.hs = hs; A.hid_w = hid_w; A.hid_b = hid_b;
  A.sa_in_w = sa_in_w; A.sa_in_b = sa_in_b; A.sa_out_w = sa_out_w; A.sa_out_b = sa_out_b;
  A.ca_in_w = ca_in_w; A.ca_in_b = ca_in_b; A.ca_out_w = ca_out_w; A.ca_out_b = ca_out_b;
  A.ln1_g = ln1_g; A.ln1_b = ln1_b; A.ln2_g = ln2_g; A.ln2_b = ln2_b; A.ln3_g = ln3_g; A.ln3_b = ln3_b;
  A.ff1_w = ff1_w; A.ff1_b = ff1_b; A.ff2_w = ff2_w; A.ff2_b = ff2_b;
  A.vr_w = vr_w; A.vr_b = vr_b; A.vm_w = vm_w; A.vm_b = vm_b; A.obj_w = obj_w;
  A.Cm = Cm; A.WqF = WqF; A.WkF = WkF; A.WvF = WvF;
  A.mem = mem; A.vtmp = vtmp; A.cac = cac;
  A.kc = kc; A.qv = qv; A.vcB = vcB; A.uB = uB; A.hbB = hbB; A.wB = wB; A.sB = sB;
  A.peT = peT; A.stylev = stylev; A.cbvec = cbvec;
  A.wqpeT = wqpeT; A.wkpeT = wkpeT; A.wvpeT = wvpeT;
  A.out = (float*)d_out;
  A.bar = bar;

  void* params[1] = { &A };
  hipError_t e = hipLaunchCooperativeKernel((void*)decode_loop, dim3(NBLK), dim3(TPB), params, 0, stream);
  if (e != hipSuccess){
    decode_loop<<<dim3(NBLK), dim3(TPB), 0, stream>>>(A);
  }
}

// Round 17
// 2028.965 us; speedup vs baseline: 1.8821x; 1.8821x over previous
//
#include <hip/hip_runtime.h>
#include <math.h>

#define DIM  1024
#define SEQ  64
#define HDIM 256
#define NBLK 256
#define TPB  256
#define SLOT_STRIDE 32      // 32 u32 = 128 B
#define SENTU 0xFFC00ABCu   // NaN sentinel: computations never produce this pattern

// ---------------- wave / block reduction helpers ----------------
__device__ __forceinline__ float wsum(float v){
  v += __shfl_xor(v, 32, 64); v += __shfl_xor(v, 16, 64); v += __shfl_xor(v, 8, 64);
  v += __shfl_xor(v, 4, 64);  v += __shfl_xor(v, 2, 64);  v += __shfl_xor(v, 1, 64);
  return v;
}
__device__ __forceinline__ float wmax(float v){
  v = fmaxf(v, __shfl_xor(v, 32, 64)); v = fmaxf(v, __shfl_xor(v, 16, 64));
  v = fmaxf(v, __shfl_xor(v, 8, 64));  v = fmaxf(v, __shfl_xor(v, 4, 64));
  v = fmaxf(v, __shfl_xor(v, 2, 64));  v = fmaxf(v, __shfl_xor(v, 1, 64));
  return v;
}
__device__ __forceinline__ float2 breduce2(float va, float vb, float* red){
  int tid = threadIdx.x;
  va = wsum(va); vb = wsum(vb);
  if ((tid & 63) == 0){ red[(tid >> 6) * 2] = va; red[(tid >> 6) * 2 + 1] = vb; }
  __syncthreads();
  float ra = red[0] + red[2] + red[4] + red[6];
  float rb = red[1] + red[3] + red[5] + red[7];
  __syncthreads();
  return make_float2(ra, rb);
}

// ---------------- device-coherent primitives (R8-proven) ----------------
__device__ __forceinline__ float ldc(const float* p){
  return __hip_atomic_load(p, __ATOMIC_RELAXED, __HIP_MEMORY_SCOPE_AGENT);
}
__device__ __forceinline__ void stc(float* p, float v){
  __hip_atomic_store(p, v, __ATOMIC_RELAXED, __HIP_MEMORY_SCOPE_AGENT);
}
__device__ __forceinline__ void sta(unsigned* p, unsigned v){
  __hip_atomic_store(p, v, __ATOMIC_RELAXED, __HIP_MEMORY_SCOPE_AGENT);
}
// sentinel polls: value arrives with its own validity (one-phase handoff)
__device__ __forceinline__ void poll4s(const float* p, int stride, float* out){
  float v0 = ldc(p), v1 = ldc(p + stride), v2 = ldc(p + 2 * stride), v3 = ldc(p + 3 * stride);
  unsigned s = 0;
  while (__float_as_uint(v0) == SENTU || __float_as_uint(v1) == SENTU ||
         __float_as_uint(v2) == SENTU || __float_as_uint(v3) == SENTU){
    v0 = ldc(p); v1 = ldc(p + stride); v2 = ldc(p + 2 * stride); v3 = ldc(p + 3 * stride);
    if (++s > 200000000u) break;
  }
  out[0] = v0; out[1] = v1; out[2] = v2; out[3] = v3;
}
__device__ __forceinline__ void poll8s(const float* p, float* out){
  unsigned s = 0;
  for (;;){
    bool ok = true;
    #pragma unroll
    for (int m = 0; m < 8; ++m){ out[m] = ldc(p + 64 * m); }
    #pragma unroll
    for (int m = 0; m < 8; ++m) ok = ok && (__float_as_uint(out[m]) != SENTU);
    if (ok) return;
    if (++s > 50000000u) return;
  }
}
__device__ __forceinline__ void spin_ge(unsigned* p, unsigned ep){
  unsigned spins = 0;
  while (__hip_atomic_load(p, __ATOMIC_RELAXED, __HIP_MEMORY_SCOPE_AGENT) < ep){
    if (++spins > 100000000u) break;
  }
}
// flat barrier (R8-proven), prologue stages only
__device__ __forceinline__ void gsync(unsigned* slots, unsigned ep, int bid, int tid){
  asm volatile("s_waitcnt vmcnt(0)" ::: "memory");
  __syncthreads();
  if (tid == 0) sta(&slots[bid * SLOT_STRIDE], ep);
  spin_ge(&slots[tid * SLOT_STRIDE], ep);
  __syncthreads();
  asm volatile("" ::: "memory");
}

// ---------------- prologue matmul: 64x64 tile, 4x4 per thread ----------------
__global__ void mm1024(const float* __restrict__ A0, const float* __restrict__ B,
                       float* __restrict__ C0, size_t Astride, size_t Cstride){
  const float* A = A0 + (size_t)blockIdx.z * Astride;
  float* C = C0 + (size_t)blockIdx.z * Cstride;
  __shared__ float As[16][65];
  __shared__ float Bs[16][65];
  int ta = blockIdx.y * 64, tb = blockIdx.x * 64;
  int tx = threadIdx.x & 15, ty = threadIdx.x >> 4;
  float acc[4][4] = {};
  for (int k0 = 0; k0 < 1024; k0 += 16){
    #pragma unroll
    for (int j = 0; j < 4; ++j)
      As[tx][ty * 4 + j] = A[(size_t)(ta + ty * 4 + j) * 1024 + k0 + tx];
    {
      const float4 bv = *(const float4*)&B[(size_t)(k0 + ty) * 1024 + tb + tx * 4];
      Bs[ty][tx * 4]     = bv.x; Bs[ty][tx * 4 + 1] = bv.y;
      Bs[ty][tx * 4 + 2] = bv.z; Bs[ty][tx * 4 + 3] = bv.w;
    }
    __syncthreads();
    #pragma unroll
    for (int kk = 0; kk < 16; ++kk){
      float av[4], bv[4];
      #pragma unroll
      for (int m = 0; m < 4; ++m) av[m] = As[kk][ty * 4 + m];
      #pragma unroll
      for (int n = 0; n < 4; ++n) bv[n] = Bs[kk][tx * 4 + n];
      #pragma unroll
      for (int m = 0; m < 4; ++m)
        #pragma unroll
        for (int n = 0; n < 4; ++n) acc[m][n] = fmaf(av[m], bv[n], acc[m][n]);
    }
    __syncthreads();
  }
  #pragma unroll
  for (int m = 0; m < 4; ++m){
    float4 ov = { acc[m][0], acc[m][1], acc[m][2], acc[m][3] };
    *(float4*)&C[(size_t)(ta + ty * 4 + m) * 1024 + tb + tx * 4] = ov;
  }
}

// sentinel-fill the write-once dataflow arrays (runs every launch; re-poison safe)
__global__ void sentinit(unsigned* p, size_t n){
  size_t idx = (size_t)blockIdx.x * 256 + threadIdx.x;
  for (size_t k = idx; k < n; k += (size_t)gridDim.x * 256) p[k] = SENTU;
}

// ---------------- the persistent autoregressive decode ----------------
struct CoopArgs {
  const float *hs, *hid_w, *hid_b;
  const float *sa_in_w, *sa_in_b, *sa_out_w, *sa_out_b;
  const float *ca_in_w, *ca_in_b, *ca_out_w, *ca_out_b;
  const float *ln1_g, *ln1_b, *ln2_g, *ln2_b, *ln3_g, *ln3_b;
  const float *ff1_w, *ff1_b, *ff2_w, *ff2_b;
  const float *vr_w, *vr_b, *vm_w, *vm_b, *obj_w;
  const float *Cm, *WqF, *WkF, *WvF;
  float *mem, *vtmp, *cac;
  float *kc, *qv, *vcB, *uB, *hbB, *wB;   // write-once dataflow arrays
  float *peT, *stylev, *cbvec, *wqpeT, *wkpeT, *wvpeT;
  float *out;
  unsigned *bar;
};

__global__ void __launch_bounds__(256, 2) decode_loop(CoopArgs a){
  const int tid = threadIdx.x, bid = blockIdx.x;
  const int wave = tid >> 6, lane = tid & 63;
  const int gw = bid * 4 + wave;            // global wave id / row, 0..1023
  __shared__ float smA[2048];
  __shared__ float smB[1024];
  __shared__ float smC[1024];
  __shared__ float scp[256];
  __shared__ float red[8];
  unsigned bep = 0;
  const float NLOG = -9.210340371976184f / 1024.0f;   // -ln(10000)/D

  // ======== P1: mem rows; pe table; style vector ========
  {
    float pw[16];
    const float* pr = a.hid_w + (size_t)gw * DIM;
    #pragma unroll
    for (int k = 0; k < 16; ++k) pw[k] = pr[lane + 64 * k];
    float bias = a.hid_b[gw];
    for (int t = 0; t < 64; ++t){
      const float* xr = a.hs + (size_t)t * DIM;
      float acc = 0.f;
      #pragma unroll
      for (int k = 0; k < 16; ++k) acc = fmaf(pw[k], xr[lane + 64 * k], acc);
      acc = wsum(acc);
      if (lane == 0) stc(a.mem + (size_t)t * DIM + gw, acc + bias);
    }
    if (bid < 30){
      int p = bid;
      for (int d = tid; d < DIM; d += 256){
        float dv = __expf((float)(2 * (d >> 1)) * NLOG);
        float arg = (float)p * dv;
        stc(a.peT + (size_t)p * DIM + d, (d & 1) ? cosf(arg) : sinf(arg));
      }
    } else if (bid == 30){
      for (int d = tid; d < DIM; d += 256) stc(a.stylev + d, a.obj_w[(size_t)d * 80]);
    }
  }
  ++bep; gsync(a.bar, bep, bid, tid);

  // ======== P2: vtmp rows; cb vector ========
  float cbv;
  {
    const float* pv = a.vm_w + (size_t)gw * DIM;
    float acc = 0.f;
    #pragma unroll
    for (int k = 0; k < 16; ++k) acc = fmaf(pv[lane + 64 * k], a.vr_b[lane + 64 * k], acc);
    acc = wsum(acc);
    cbv = acc + a.vm_b[gw] + ldc(a.stylev + gw);
    if (lane == 0) stc(a.cbvec + gw, cbv);
  }
  {
    float pw[16];
    const float* pr = a.ca_in_w + (size_t)(2 * DIM + gw) * DIM;
    #pragma unroll
    for (int k = 0; k < 16; ++k) pw[k] = pr[lane + 64 * k];
    float bias = a.ca_in_b[2 * DIM + gw];
    for (int t = 0; t < 64; ++t){
      #pragma unroll
      for (int k = 0; k < 4; ++k) smA[tid + 256 * k] = ldc(a.mem + (size_t)t * DIM + tid + 256 * k);
      __syncthreads();
      float acc = 0.f;
      #pragma unroll
      for (int k = 0; k < 16; ++k) acc = fmaf(pw[k], smA[lane + 64 * k], acc);
      acc = wsum(acc);
      if (lane == 0) stc(a.vtmp + (size_t)t * DIM + gw, acc + bias);
      __syncthreads();
    }
  }
  ++bep; gsync(a.bar, bep, bid, tid);

  // ======== P3: cac rows ========
  {
    float pw[16];
    const float* pr = a.ca_out_w + (size_t)gw * DIM;
    #pragma unroll
    for (int k = 0; k < 16; ++k) pw[k] = pr[lane + 64 * k];
    float bias = a.ca_out_b[gw];
    for (int t = 0; t < 64; ++t){
      #pragma unroll
      for (int k = 0; k < 4; ++k) smA[tid + 256 * k] = ldc(a.vtmp + (size_t)t * DIM + tid + 256 * k);
      __syncthreads();
      float acc = 0.f;
      #pragma unroll
      for (int k = 0; k < 16; ++k) acc = fmaf(pw[k], smA[lane + 64 * k], acc);
      acc = wsum(acc);
      if (lane == 0) stc(a.cac + (size_t)t * DIM + gw, acc + bias);
      __syncthreads();
    }
  }
  ++bep; gsync(a.bar, bep, bid, tid);

  // ======== PB: per-row QKV constants (W.cb, W.style, W.pe[p]); publish i=0 q/k/v ========
  float aqcb, akcb, avcb;
  {
    float wqr[16], wkr[16], wvr[16];
    const float* pq = a.sa_in_w + (size_t)gw * DIM;
    const float* pk = a.sa_in_w + (size_t)(DIM + gw) * DIM;
    const float* pv = a.sa_in_w + (size_t)(2 * DIM + gw) * DIM;
    #pragma unroll
    for (int k = 0; k < 16; ++k){
      int d = lane + 64 * k;
      wqr[k] = pq[d]; wkr[k] = pk[d]; wvr[k] = pv[d];
    }
    const float b_q = a.sa_in_b[gw];
    const float b_k = a.sa_in_b[DIM + gw];
    const float b_v = a.sa_in_b[2 * DIM + gw];
    float dq = 0.f, dk = 0.f, dv = 0.f, sq = 0.f, sk = 0.f, sv = 0.f;
    #pragma unroll
    for (int k = 0; k < 16; ++k){
      float xc = ldc(a.cbvec + lane + 64 * k);
      float xs = ldc(a.stylev + lane + 64 * k);
      dq = fmaf(wqr[k], xc, dq); dk = fmaf(wkr[k], xc, dk); dv = fmaf(wvr[k], xc, dv);
      sq = fmaf(wqr[k], xs, sq); sk = fmaf(wkr[k], xs, sk); sv = fmaf(wvr[k], xs, sv);
    }
    aqcb = wsum(dq) + b_q; akcb = wsum(dk) + b_k; avcb = wsum(dv) + b_v;
    sq = wsum(sq); sk = wsum(sk); sv = wsum(sv);
    float pq0 = 0.f, pk0 = 0.f, pv0 = 0.f;
    for (int p = 0; p < 30; ++p){
      const float* pp = a.peT + (size_t)p * DIM;
      float tq = 0.f, tk = 0.f, tv = 0.f;
      #pragma unroll
      for (int k = 0; k < 16; ++k){
        float x = ldc(pp + lane + 64 * k);
        tq = fmaf(wqr[k], x, tq); tk = fmaf(wkr[k], x, tk); tv = fmaf(wvr[k], x, tv);
      }
      tq = wsum(tq); tk = wsum(tk); tv = wsum(tv);
      if (lane == 0){
        stc(a.wqpeT + (size_t)p * DIM + gw, tq);
        stc(a.wkpeT + (size_t)p * DIM + gw, tk);
        stc(a.wvpeT + (size_t)p * DIM + gw, tv);
      }
      if (p == 0){ pq0 = tq; pk0 = tk; pv0 = tv; }
    }
    if (lane == 0){
      stc(a.qv + gw, sq + pq0 + b_q);
      stc(a.kc + gw, sk + pk0 + b_k);
      stc(a.vcB + gw, sv + pv0 + b_v);
    }
  }
  ++bep; gsync(a.bar, bep, bid, tid);   // wqpeT tables must be globally visible

  // ---- preload folded/main weight rows (128 floats/thread)
  float fq[16], fk[16], fv[16], wo[16], f1a[16], f1b[16], f2[32];
  {
    const float* pq = a.WqF + (size_t)gw * DIM;
    const float* pk = a.WkF + (size_t)gw * DIM;
    const float* pv = a.WvF + (size_t)gw * DIM;
    const float* po = a.sa_out_w + (size_t)gw * DIM;
    const float* p1a = a.ff1_w + (size_t)(2 * gw) * DIM;
    const float* p1b = a.ff1_w + (size_t)(2 * gw + 1) * DIM;
    const float* p2 = a.ff2_w + (size_t)gw * 2048;
    #pragma unroll
    for (int k = 0; k < 16; ++k){
      int d = lane + 64 * k;
      fq[k] = pq[d]; fk[k] = pk[d]; fv[k] = pv[d]; wo[k] = po[d];
      f1a[k] = p1a[d]; f1b[k] = p1b[d];
    }
    #pragma unroll
    for (int k = 0; k < 32; ++k) f2[k] = p2[lane + 64 * k];
  }
  const float b_o  = a.sa_out_b[gw];
  const float b_1a = a.ff1_b[2 * gw];
  const float b_1b = a.ff1_b[2 * gw + 1];
  const float b_2  = a.ff2_b[gw];
  const float b_vr = a.vr_b[gw];

  float c0 = 0.f, c1 = 0.f, c2 = 0.f, c3 = 0.f;
  float xres = a.obj_w[(size_t)gw * 80] + ldc(a.peT + gw);
  float vrr[16], cmr[16];

  for (int i = 0; i < SEQ; ++i){
    // ---- MS2: attention -> u  (all local: poll V row + q row + K rows)
    {
      float vv[4], qq[4];
      poll4s(a.vcB + (size_t)i * DIM + tid, 256, vv);
      poll4s(a.qv + (size_t)i * DIM + tid, 256, qq);
      smB[tid] = vv[0]; smB[tid + 256] = vv[1]; smB[tid + 512] = vv[2]; smB[tid + 768] = vv[3];
      smC[tid] = qq[0]; smC[tid + 256] = qq[1]; smC[tid + 512] = qq[2]; smC[tid + 768] = qq[3];
      __syncthreads();
      // c-update from V row
      float p0 = 0.f, p1 = 0.f, p2 = 0.f, p3 = 0.f;
      #pragma unroll
      for (int k = 0; k < 4; ++k){
        p0 = fmaf(wo[k],      smB[lane + 64 * k],        p0);
        p1 = fmaf(wo[k + 4],  smB[lane + 64 * (k + 4)],  p1);
        p2 = fmaf(wo[k + 8],  smB[lane + 64 * (k + 8)],  p2);
        p3 = fmaf(wo[k + 12], smB[lane + 64 * (k + 12)], p3);
      }
      p0 = wsum(p0); p1 = wsum(p1); p2 = wsum(p2); p3 = wsum(p3);
      if (lane == i){ c0 = p0; c1 = p1; c2 = p2; c3 = p3; }
      // scores computed locally: wave handles j = wave, wave+4, ... (all 4 heads)
      for (int j = wave; j <= i; j += 4){
        const float* kr = a.kc + (size_t)j * DIM + lane;
        float kv[8];
        float s0 = 0.f, s1 = 0.f, s2 = 0.f, s3 = 0.f;
        poll8s(kr, kv);                 // heads 0,1 (dims 0..511)
        #pragma unroll
        for (int mm = 0; mm < 4; ++mm){
          s0 = fmaf(smC[lane + 64 * mm],       kv[mm],     s0);
          s1 = fmaf(smC[256 + lane + 64 * mm], kv[4 + mm], s1);
        }
        poll8s(kr + 512, kv);           // heads 2,3 (dims 512..1023)
        #pragma unroll
        for (int mm = 0; mm < 4; ++mm){
          s2 = fmaf(smC[512 + lane + 64 * mm], kv[mm],     s2);
          s3 = fmaf(smC[768 + lane + 64 * mm], kv[4 + mm], s3);
        }
        s0 = wsum(s0); s1 = wsum(s1); s2 = wsum(s2); s3 = wsum(s3);
        if (lane == 0){
          float ab = (float)((i - j) / 30);
          scp[j]       = s0 * 0.0625f - 0.25f       * ab;
          scp[64 + j]  = s1 * 0.0625f - 0.0625f     * ab;
          scp[128 + j] = s2 * 0.0625f - 0.015625f   * ab;
          scp[192 + j] = s3 * 0.0625f - 0.00390625f * ab;
        }
      }
      __syncthreads();
      // softmax: wave = head (block has exactly 4 waves)
      {
        float sv = (lane <= i) ? scp[wave * 64 + lane] : -3.0e38f;
        float mx = wmax(sv);
        float p = (lane <= i) ? __expf(sv - mx) : 0.f;
        float sum = wsum(p);
        scp[wave * 64 + lane] = p / sum;
      }
      __syncthreads();
      float t = scp[lane] * c0 + scp[64 + lane] * c1 + scp[128 + lane] * c2 + scp[192 + lane] * c3;
      t = wsum(t);
      if (lane == 0) stc(a.uB + (size_t)i * DIM + gw, xres + t + b_o);
      __syncthreads();
    }

    // ---- MS3: ln1 -> +cac -> ln2 ; ff1 -> hb
    float x2v;
    {
      float cr[4];
      #pragma unroll
      for (int k = 0; k < 4; ++k) cr[k] = ldc(a.cac + (size_t)i * DIM + tid + 256 * k);
      float uv[4];
      poll4s(a.uB + (size_t)i * DIM + tid, 256, uv);
      smA[tid] = uv[0]; smA[tid + 256] = uv[1]; smA[tid + 512] = uv[2]; smA[tid + 768] = uv[3];
      __syncthreads();
      float sa = 0.f, sb = 0.f;
      #pragma unroll
      for (int k = 0; k < 4; ++k){ float x = smA[tid + 256 * k]; sa += x; sb = fmaf(x, x, sb); }
      float2 r = breduce2(sa, sb, red);
      float mean = r.x * (1.f / 1024.f);
      float var  = r.y * (1.f / 1024.f) - mean * mean;
      float rs = 1.f / sqrtf(var + 1e-5f);
      float tv[4];
      float ta = 0.f, tb = 0.f;
      #pragma unroll
      for (int k = 0; k < 4; ++k){
        int d = tid + 256 * k;
        float x1 = (smA[d] - mean) * rs * a.ln1_g[d] + a.ln1_b[d];
        tv[k] = x1 + cr[k];
        ta += tv[k]; tb = fmaf(tv[k], tv[k], tb);
      }
      float2 r2v = breduce2(ta, tb, red);
      float mean2 = r2v.x * (1.f / 1024.f);
      float var2  = r2v.y * (1.f / 1024.f) - mean2 * mean2;
      float rs2 = 1.f / sqrtf(var2 + 1e-5f);
      #pragma unroll
      for (int k = 0; k < 4; ++k){
        int d = tid + 256 * k;
        smA[d] = (tv[k] - mean2) * rs2 * a.ln2_g[d] + a.ln2_b[d];
      }
      __syncthreads();
      x2v = smA[gw];
      float acc0 = 0.f, acc1 = 0.f;
      #pragma unroll
      for (int k = 0; k < 16; ++k){
        float x = smA[lane + 64 * k];
        acc0 = fmaf(f1a[k], x, acc0);
        acc1 = fmaf(f1b[k], x, acc1);
      }
      acc0 = wsum(acc0); acc1 = wsum(acc1);
      if (lane == 0){
        stc(a.hbB + (size_t)i * 2048 + 2 * gw,     fmaxf(acc0 + b_1a, 0.f));
        stc(a.hbB + (size_t)i * 2048 + 2 * gw + 1, fmaxf(acc1 + b_1b, 0.f));
      }
      __syncthreads();
    }

    // ---- MS4: ff2 -> w ; prefetch vr_w/Cm rows
    {
      const float* pr = a.vr_w + (size_t)gw * DIM;
      const float* pc = a.Cm + (size_t)gw * DIM;
      #pragma unroll
      for (int k = 0; k < 16; ++k){ vrr[k] = pr[lane + 64 * k]; cmr[k] = pc[lane + 64 * k]; }
      float h0[4], h1[4];
      poll4s(a.hbB + (size_t)i * 2048 + tid, 256, h0);
      poll4s(a.hbB + (size_t)i * 2048 + 1024 + tid, 256, h1);
      #pragma unroll
      for (int k = 0; k < 4; ++k){ smA[tid + 256 * k] = h0[k]; smA[tid + 1024 + 256 * k] = h1[k]; }
      __syncthreads();
      float acc = 0.f;
      #pragma unroll
      for (int k = 0; k < 32; ++k) acc = fmaf(f2[k], smA[lane + 64 * k], acc);
      acc = wsum(acc);
      if (lane == 0) stc(a.wB + (size_t)i * DIM + gw, x2v + acc + b_2);
      __syncthreads();
    }

    // ---- MS1': ln3 -> y ; out row i ; folded QKV + residual for i+1
    {
      float wv4[4];
      poll4s(a.wB + (size_t)i * DIM + tid, 256, wv4);
      smA[tid] = wv4[0]; smA[tid + 256] = wv4[1]; smA[tid + 512] = wv4[2]; smA[tid + 768] = wv4[3];
      __syncthreads();
      float sa = 0.f, sb = 0.f;
      #pragma unroll
      for (int k = 0; k < 4; ++k){ float x = smA[tid + 256 * k]; sa += x; sb = fmaf(x, x, sb); }
      float2 r = breduce2(sa, sb, red);
      float mean = r.x * (1.f / 1024.f);
      float var  = r.y * (1.f / 1024.f) - mean * mean;
      float rs = 1.f / sqrtf(var + 1e-5f);
      float ov[4];
      #pragma unroll
      for (int k = 0; k < 4; ++k){
        int d = tid + 256 * k;
        ov[k] = (smA[d] - mean) * rs * a.ln3_g[d] + a.ln3_b[d];
      }
      __syncthreads();
      #pragma unroll
      for (int k = 0; k < 4; ++k) smA[tid + 256 * k] = ov[k];
      __syncthreads();
      float ar = 0.f, ac = 0.f, aqn = 0.f, akn = 0.f, avn = 0.f;
      #pragma unroll
      for (int k = 0; k < 16; ++k){
        float x = smA[lane + 64 * k];
        ar  = fmaf(vrr[k], x, ar);
        ac  = fmaf(cmr[k], x, ac);
        aqn = fmaf(fq[k], x, aqn);
        akn = fmaf(fk[k], x, akn);
        avn = fmaf(fv[k], x, avn);
      }
      ar = wsum(ar); ac = wsum(ac);
      aqn = wsum(aqn); akn = wsum(akn); avn = wsum(avn);
      if (lane == 0) a.out[(size_t)i * DIM + gw] = ar + b_vr;
      if (i < SEQ - 1){
        int pn = (i + 1) % 30;
        if (lane == 0){
          float tq = ldc(a.wqpeT + (size_t)pn * DIM + gw);
          float tk = ldc(a.wkpeT + (size_t)pn * DIM + gw);
          float tv = ldc(a.wvpeT + (size_t)pn * DIM + gw);
          stc(a.qv + (size_t)(i + 1) * DIM + gw, aqn + aqcb + tq);
          stc(a.kc + (size_t)(i + 1) * DIM + gw, akn + akcb + tk);
          stc(a.vcB + (size_t)(i + 1) * DIM + gw, avn + avcb + tv);
        }
        xres = ac + cbv + ldc(a.peT + (size_t)pn * DIM + gw);
      }
      __syncthreads();
    }
  }
}

// ---------------- host launcher ----------------
extern "C" void kernel_launch(void* const* d_in, const int* in_sizes, int n_in,
                              void* d_out, int out_size, void* d_ws, size_t ws_size,
                              hipStream_t stream){
  const float* hs       = (const float*)d_in[0];
  const float* hid_w    = (const float*)d_in[1];
  const float* hid_b    = (const float*)d_in[2];
  const float* obj_w    = (const float*)d_in[3];
  const float* sa_in_w  = (const float*)d_in[4];
  const float* sa_in_b  = (const float*)d_in[5];
  const float* sa_out_w = (const float*)d_in[6];
  const float* sa_out_b = (const float*)d_in[7];
  const float* ca_in_w  = (const float*)d_in[8];
  const float* ca_in_b  = (const float*)d_in[9];
  const float* ca_out_w = (const float*)d_in[10];
  const float* ca_out_b = (const float*)d_in[11];
  const float* ln1_g    = (const float*)d_in[12];
  const float* ln1_b    = (const float*)d_in[13];
  const float* ln2_g    = (const float*)d_in[14];
  const float* ln2_b    = (const float*)d_in[15];
  const float* ln3_g    = (const float*)d_in[16];
  const float* ln3_b    = (const float*)d_in[17];
  const float* ff1_w    = (const float*)d_in[18];
  const float* ff1_b    = (const float*)d_in[19];
  const float* ff2_w    = (const float*)d_in[20];
  const float* ff2_b    = (const float*)d_in[21];
  const float* vr_w     = (const float*)d_in[22];
  const float* vr_b     = (const float*)d_in[23];
  const float* vm_w     = (const float*)d_in[24];
  const float* vm_b     = (const float*)d_in[25];

  float* ws = (float*)d_ws;
  float* mem    = ws;                 // 65536
  float* vtmp   = ws + 65536;         // 65536
  float* cac    = ws + 131072;        // 65536
  // ---- write-once dataflow region (sentinel-initialized each launch) ----
  float* kc     = ws + 196608;        // 65536  [64][1024]
  float* qv     = ws + 262144;        // 65536
  float* vcB    = ws + 327680;        // 65536
  float* uB     = ws + 393216;        // 65536
  float* hbB    = ws + 458752;        // 131072 [64][2048]
  float* wB     = ws + 589824;        // 65536
  // ---- constants / tables ----
  float* peT    = ws + 655360;        // 30720
  float* stylev = ws + 686080;        // 1024
  float* cbvec  = ws + 687104;        // 1024
  float* wqpeT  = ws + 688128;        // 30720
  float* wkpeT  = ws + 718848;        // 30720
  float* wvpeT  = ws + 749568;        // 30720
  unsigned* bar = (unsigned*)(ws + 780288);   // 256 lines x 128B = 32KB
  float* Cm     = ws + 788480;        // 1048576
  float* WqF    = ws + 1837056;       // 1048576
  float* WkF    = ws + 2885632;       // 1048576
  float* WvF    = ws + 3934208;       // 1048576 -> end 4982784 floats (~20MB)

  hipMemsetAsync((void*)bar, 0, 256 * SLOT_STRIDE * 4, stream);
  sentinit<<<512, 256, 0, stream>>>((unsigned*)kc, 458752);   // kc..wB

  mm1024<<<dim3(16, 16, 1), 256, 0, stream>>>(vm_w, vr_w, Cm, 0, 0);
  mm1024<<<dim3(16, 16, 3), 256, 0, stream>>>(sa_in_w, Cm, WqF,
                                              (size_t)1024 * 1024, (size_t)1024 * 1024);

  CoopArgs A;
  A.hs = hs; A.hid_w = hid_w; A.hid_b = hid_b;
  A.sa_in_w = sa_in_w; A.sa_in_b = sa_in_b; A.sa_out_w = sa_out_w; A.sa_out_b = sa_out_b;
  A.ca_in_w = ca_in_w; A.ca_in_b = ca_in_b; A.ca_out_w = ca_out_w; A.ca_out_b = ca_out_b;
  A.ln1_g = ln1_g; A.ln1_b = ln1_b; A.ln2_g = ln2_g; A.ln2_b = ln2_b; A.ln3_g = ln3_g; A.ln3_b = ln3_b;
  A.ff1_w = ff1_w; A.ff1_b = ff1_b; A.ff2_w = ff2_w; A.ff2_b = ff2_b;
  A.vr_w = vr_w; A.vr_b = vr_b; A.vm_w = vm_w; A.vm_b = vm_b; A.obj_w = obj_w;
  A.Cm = Cm; A.WqF = WqF; A.WkF = WkF; A.WvF = WvF;
  A.mem = mem; A.vtmp = vtmp; A.cac = cac;
  A.kc = kc; A.qv = qv; A.vcB = vcB; A.uB = uB; A.hbB = hbB; A.wB = wB;
  A.peT = peT; A.stylev = stylev; A.cbvec = cbvec;
  A.wqpeT = wqpeT; A.wkpeT = wkpeT; A.wvpeT = wvpeT;
  A.out = (float*)d_out;
  A.bar = bar;

  void* params[1] = { &A };
  hipError_t e = hipLaunchCooperativeKernel((void*)decode_loop, dim3(NBLK), dim3(TPB), params, 0, stream);
  if (e != hipSuccess){
    decode_loop<<<dim3(NBLK), dim3(TPB), 0, stream>>>(A);
  }
}

// Round 18
// 1844.353 us; speedup vs baseline: 2.0705x; 1.1001x over previous
//
#include <hip/hip_runtime.h>
#include <math.h>

#define DIM  1024
#define SEQ  64
#define HDIM 256
#define NBLK 256
#define TPB  256
#define SLOT_STRIDE 32      // 32 u32 = 128 B
#define SENTU 0xFFC00ABCu   // NaN sentinel: computations never produce this pattern

// ---------------- wave / block reduction helpers ----------------
__device__ __forceinline__ float wsum(float v){
  v += __shfl_xor(v, 32, 64); v += __shfl_xor(v, 16, 64); v += __shfl_xor(v, 8, 64);
  v += __shfl_xor(v, 4, 64);  v += __shfl_xor(v, 2, 64);  v += __shfl_xor(v, 1, 64);
  return v;
}
__device__ __forceinline__ float wmax(float v){
  v = fmaxf(v, __shfl_xor(v, 32, 64)); v = fmaxf(v, __shfl_xor(v, 16, 64));
  v = fmaxf(v, __shfl_xor(v, 8, 64));  v = fmaxf(v, __shfl_xor(v, 4, 64));
  v = fmaxf(v, __shfl_xor(v, 2, 64));  v = fmaxf(v, __shfl_xor(v, 1, 64));
  return v;
}
__device__ __forceinline__ float2 breduce2(float va, float vb, float* red){
  int tid = threadIdx.x;
  va = wsum(va); vb = wsum(vb);
  if ((tid & 63) == 0){ red[(tid >> 6) * 2] = va; red[(tid >> 6) * 2 + 1] = vb; }
  __syncthreads();
  float ra = red[0] + red[2] + red[4] + red[6];
  float rb = red[1] + red[3] + red[5] + red[7];
  __syncthreads();
  return make_float2(ra, rb);
}

// ---------------- device-coherent primitives (R8-proven) ----------------
__device__ __forceinline__ float ldc(const float* p){
  return __hip_atomic_load(p, __ATOMIC_RELAXED, __HIP_MEMORY_SCOPE_AGENT);
}
__device__ __forceinline__ void stc(float* p, float v){
  __hip_atomic_store(p, v, __ATOMIC_RELAXED, __HIP_MEMORY_SCOPE_AGENT);
}
__device__ __forceinline__ void sta(unsigned* p, unsigned v){
  __hip_atomic_store(p, v, __ATOMIC_RELAXED, __HIP_MEMORY_SCOPE_AGENT);
}
// sentinel polls (one-phase handoff; only for data whose freshness isn't implied)
__device__ __forceinline__ void poll4s(const float* p, int stride, float* out){
  float v0 = ldc(p), v1 = ldc(p + stride), v2 = ldc(p + 2 * stride), v3 = ldc(p + 3 * stride);
  unsigned s = 0;
  while (__float_as_uint(v0) == SENTU || __float_as_uint(v1) == SENTU ||
         __float_as_uint(v2) == SENTU || __float_as_uint(v3) == SENTU){
    v0 = ldc(p); v1 = ldc(p + stride); v2 = ldc(p + 2 * stride); v3 = ldc(p + 3 * stride);
    if (++s > 200000000u) break;
  }
  out[0] = v0; out[1] = v1; out[2] = v2; out[3] = v3;
}
// combined poll of two 4-strided groups (one spin loop, one detect round trip)
__device__ __forceinline__ void poll8x(const float* p1, const float* p2, int stride,
                                       float* o1, float* o2){
  unsigned s = 0;
  for (;;){
    bool ok = true;
    #pragma unroll
    for (int m = 0; m < 4; ++m){ o1[m] = ldc(p1 + m * stride); o2[m] = ldc(p2 + m * stride); }
    #pragma unroll
    for (int m = 0; m < 4; ++m)
      ok = ok && (__float_as_uint(o1[m]) != SENTU) && (__float_as_uint(o2[m]) != SENTU);
    if (ok) return;
    if (++s > 200000000u) return;
  }
}
__device__ __forceinline__ void poll8s(const float* p, float* out){
  unsigned s = 0;
  for (;;){
    bool ok = true;
    #pragma unroll
    for (int m = 0; m < 8; ++m){ out[m] = ldc(p + 64 * m); }
    #pragma unroll
    for (int m = 0; m < 8; ++m) ok = ok && (__float_as_uint(out[m]) != SENTU);
    if (ok) return;
    if (++s > 50000000u) return;
  }
}
__device__ __forceinline__ void spin_ge(unsigned* p, unsigned ep){
  unsigned spins = 0;
  while (__hip_atomic_load(p, __ATOMIC_RELAXED, __HIP_MEMORY_SCOPE_AGENT) < ep){
    if (++spins > 100000000u) break;
  }
}
// flat barrier (R8-proven), prologue stages only
__device__ __forceinline__ void gsync(unsigned* slots, unsigned ep, int bid, int tid){
  asm volatile("s_waitcnt vmcnt(0)" ::: "memory");
  __syncthreads();
  if (tid == 0) sta(&slots[bid * SLOT_STRIDE], ep);
  spin_ge(&slots[tid * SLOT_STRIDE], ep);
  __syncthreads();
  asm volatile("" ::: "memory");
}

// ---------------- prologue matmul: 64x64 tile, 4x4 per thread ----------------
__global__ void mm1024(const float* __restrict__ A0, const float* __restrict__ B,
                       float* __restrict__ C0, size_t Astride, size_t Cstride){
  const float* A = A0 + (size_t)blockIdx.z * Astride;
  float* C = C0 + (size_t)blockIdx.z * Cstride;
  __shared__ float As[16][65];
  __shared__ float Bs[16][65];
  int ta = blockIdx.y * 64, tb = blockIdx.x * 64;
  int tx = threadIdx.x & 15, ty = threadIdx.x >> 4;
  float acc[4][4] = {};
  for (int k0 = 0; k0 < 1024; k0 += 16){
    #pragma unroll
    for (int j = 0; j < 4; ++j)
      As[tx][ty * 4 + j] = A[(size_t)(ta + ty * 4 + j) * 1024 + k0 + tx];
    {
      const float4 bv = *(const float4*)&B[(size_t)(k0 + ty) * 1024 + tb + tx * 4];
      Bs[ty][tx * 4]     = bv.x; Bs[ty][tx * 4 + 1] = bv.y;
      Bs[ty][tx * 4 + 2] = bv.z; Bs[ty][tx * 4 + 3] = bv.w;
    }
    __syncthreads();
    #pragma unroll
    for (int kk = 0; kk < 16; ++kk){
      float av[4], bv[4];
      #pragma unroll
      for (int m = 0; m < 4; ++m) av[m] = As[kk][ty * 4 + m];
      #pragma unroll
      for (int n = 0; n < 4; ++n) bv[n] = Bs[kk][tx * 4 + n];
      #pragma unroll
      for (int m = 0; m < 4; ++m)
        #pragma unroll
        for (int n = 0; n < 4; ++n) acc[m][n] = fmaf(av[m], bv[n], acc[m][n]);
    }
    __syncthreads();
  }
  #pragma unroll
  for (int m = 0; m < 4; ++m){
    float4 ov = { acc[m][0], acc[m][1], acc[m][2], acc[m][3] };
    *(float4*)&C[(size_t)(ta + ty * 4 + m) * 1024 + tb + tx * 4] = ov;
  }
}

// sentinel-fill the write-once dataflow arrays (runs every launch; re-poison safe)
__global__ void sentinit(unsigned* p, size_t n){
  size_t idx = (size_t)blockIdx.x * 256 + threadIdx.x;
  for (size_t k = idx; k < n; k += (size_t)gridDim.x * 256) p[k] = SENTU;
}

// ---------------- the persistent autoregressive decode ----------------
struct CoopArgs {
  const float *hs, *hid_w, *hid_b;
  const float *sa_in_w, *sa_in_b, *sa_out_w, *sa_out_b;
  const float *ca_in_w, *ca_in_b, *ca_out_w, *ca_out_b;
  const float *ln1_g, *ln1_b, *ln2_g, *ln2_b, *ln3_g, *ln3_b;
  const float *ff1_w, *ff1_b, *ff2_w, *ff2_b;
  const float *vr_w, *vr_b, *vm_w, *vm_b, *obj_w;
  const float *Cm, *WqF, *WkF, *WvF;
  float *mem, *vtmp, *cac;
  float *kc, *qv, *vcB, *uB, *hbB, *wB;   // write-once dataflow arrays
  float *peT, *stylev, *cbvec, *wqpeT, *wkpeT, *wvpeT;
  float *out;
  unsigned *bar;
};

__global__ void __launch_bounds__(256, 1) decode_loop(CoopArgs a){
  const int tid = threadIdx.x, bid = blockIdx.x;
  const int wave = tid >> 6, lane = tid & 63;
  const int gw = bid * 4 + wave;            // global wave id / row, 0..1023
  __shared__ float smA[2048];
  __shared__ float smB[1024];
  __shared__ float smC[1024];
  __shared__ float scp[256];
  __shared__ float red[8];
  unsigned bep = 0;
  const float NLOG = -9.210340371976184f / 1024.0f;   // -ln(10000)/D

  // ======== P1: mem rows; pe table; style vector ========
  {
    float pw[16];
    const float* pr = a.hid_w + (size_t)gw * DIM;
    #pragma unroll
    for (int k = 0; k < 16; ++k) pw[k] = pr[lane + 64 * k];
    float bias = a.hid_b[gw];
    for (int t = 0; t < 64; ++t){
      const float* xr = a.hs + (size_t)t * DIM;
      float acc = 0.f;
      #pragma unroll
      for (int k = 0; k < 16; ++k) acc = fmaf(pw[k], xr[lane + 64 * k], acc);
      acc = wsum(acc);
      if (lane == 0) stc(a.mem + (size_t)t * DIM + gw, acc + bias);
    }
    if (bid < 30){
      int p = bid;
      for (int d = tid; d < DIM; d += 256){
        float dv = __expf((float)(2 * (d >> 1)) * NLOG);
        float arg = (float)p * dv;
        stc(a.peT + (size_t)p * DIM + d, (d & 1) ? cosf(arg) : sinf(arg));
      }
    } else if (bid == 30){
      for (int d = tid; d < DIM; d += 256) stc(a.stylev + d, a.obj_w[(size_t)d * 80]);
    }
  }
  ++bep; gsync(a.bar, bep, bid, tid);

  // ======== P2: vtmp rows; cb vector ========
  float cbv;
  {
    const float* pv = a.vm_w + (size_t)gw * DIM;
    float acc = 0.f;
    #pragma unroll
    for (int k = 0; k < 16; ++k) acc = fmaf(pv[lane + 64 * k], a.vr_b[lane + 64 * k], acc);
    acc = wsum(acc);
    cbv = acc + a.vm_b[gw] + ldc(a.stylev + gw);
    if (lane == 0) stc(a.cbvec + gw, cbv);
  }
  {
    float pw[16];
    const float* pr = a.ca_in_w + (size_t)(2 * DIM + gw) * DIM;
    #pragma unroll
    for (int k = 0; k < 16; ++k) pw[k] = pr[lane + 64 * k];
    float bias = a.ca_in_b[2 * DIM + gw];
    for (int t = 0; t < 64; ++t){
      #pragma unroll
      for (int k = 0; k < 4; ++k) smA[tid + 256 * k] = ldc(a.mem + (size_t)t * DIM + tid + 256 * k);
      __syncthreads();
      float acc = 0.f;
      #pragma unroll
      for (int k = 0; k < 16; ++k) acc = fmaf(pw[k], smA[lane + 64 * k], acc);
      acc = wsum(acc);
      if (lane == 0) stc(a.vtmp + (size_t)t * DIM + gw, acc + bias);
      __syncthreads();
    }
  }
  ++bep; gsync(a.bar, bep, bid, tid);

  // ======== P3: cac rows ========
  {
    float pw[16];
    const float* pr = a.ca_out_w + (size_t)gw * DIM;
    #pragma unroll
    for (int k = 0; k < 16; ++k) pw[k] = pr[lane + 64 * k];
    float bias = a.ca_out_b[gw];
    for (int t = 0; t < 64; ++t){
      #pragma unroll
      for (int k = 0; k < 4; ++k) smA[tid + 256 * k] = ldc(a.vtmp + (size_t)t * DIM + tid + 256 * k);
      __syncthreads();
      float acc = 0.f;
      #pragma unroll
      for (int k = 0; k < 16; ++k) acc = fmaf(pw[k], smA[lane + 64 * k], acc);
      acc = wsum(acc);
      if (lane == 0) stc(a.cac + (size_t)t * DIM + gw, acc + bias);
      __syncthreads();
    }
  }
  ++bep; gsync(a.bar, bep, bid, tid);

  // ======== PB: per-row QKV constants (W.cb, W.style, W.pe[p]); publish i=0 q/k/v ========
  float aqcb, akcb, avcb;
  {
    float wqr[16], wkr[16], wvr[16];
    const float* pq = a.sa_in_w + (size_t)gw * DIM;
    const float* pk = a.sa_in_w + (size_t)(DIM + gw) * DIM;
    const float* pv = a.sa_in_w + (size_t)(2 * DIM + gw) * DIM;
    #pragma unroll
    for (int k = 0; k < 16; ++k){
      int d = lane + 64 * k;
      wqr[k] = pq[d]; wkr[k] = pk[d]; wvr[k] = pv[d];
    }
    const float b_q = a.sa_in_b[gw];
    const float b_k = a.sa_in_b[DIM + gw];
    const float b_v = a.sa_in_b[2 * DIM + gw];
    float dq = 0.f, dk = 0.f, dv = 0.f, sq = 0.f, sk = 0.f, sv = 0.f;
    #pragma unroll
    for (int k = 0; k < 16; ++k){
      float xc = ldc(a.cbvec + lane + 64 * k);
      float xs = ldc(a.stylev + lane + 64 * k);
      dq = fmaf(wqr[k], xc, dq); dk = fmaf(wkr[k], xc, dk); dv = fmaf(wvr[k], xc, dv);
      sq = fmaf(wqr[k], xs, sq); sk = fmaf(wkr[k], xs, sk); sv = fmaf(wvr[k], xs, sv);
    }
    aqcb = wsum(dq) + b_q; akcb = wsum(dk) + b_k; avcb = wsum(dv) + b_v;
    sq = wsum(sq); sk = wsum(sk); sv = wsum(sv);
    float pq0 = 0.f, pk0 = 0.f, pv0 = 0.f;
    for (int p = 0; p < 30; ++p){
      const float* pp = a.peT + (size_t)p * DIM;
      float tq = 0.f, tk = 0.f, tv = 0.f;
      #pragma unroll
      for (int k = 0; k < 16; ++k){
        float x = ldc(pp + lane + 64 * k);
        tq = fmaf(wqr[k], x, tq); tk = fmaf(wkr[k], x, tk); tv = fmaf(wvr[k], x, tv);
      }
      tq = wsum(tq); tk = wsum(tk); tv = wsum(tv);
      if (lane == 0){
        stc(a.wqpeT + (size_t)p * DIM + gw, tq);
        stc(a.wkpeT + (size_t)p * DIM + gw, tk);
        stc(a.wvpeT + (size_t)p * DIM + gw, tv);
      }
      if (p == 0){ pq0 = tq; pk0 = tk; pv0 = tv; }
    }
    if (lane == 0){
      stc(a.qv + gw, sq + pq0 + b_q);
      stc(a.kc + gw, sk + pk0 + b_k);
      stc(a.vcB + gw, sv + pv0 + b_v);
    }
  }
  ++bep; gsync(a.bar, bep, bid, tid);   // wqpeT tables must be globally visible

  // ---- preload folded/main weight rows (128 floats/thread)
  float fq[16], fk[16], fv[16], wo[16], f1a[16], f1b[16], f2[32];
  {
    const float* pq = a.WqF + (size_t)gw * DIM;
    const float* pk = a.WkF + (size_t)gw * DIM;
    const float* pv = a.WvF + (size_t)gw * DIM;
    const float* po = a.sa_out_w + (size_t)gw * DIM;
    const float* p1a = a.ff1_w + (size_t)(2 * gw) * DIM;
    const float* p1b = a.ff1_w + (size_t)(2 * gw + 1) * DIM;
    const float* p2 = a.ff2_w + (size_t)gw * 2048;
    #pragma unroll
    for (int k = 0; k < 16; ++k){
      int d = lane + 64 * k;
      fq[k] = pq[d]; fk[k] = pk[d]; fv[k] = pv[d]; wo[k] = po[d];
      f1a[k] = p1a[d]; f1b[k] = p1b[d];
    }
    #pragma unroll
    for (int k = 0; k < 32; ++k) f2[k] = p2[lane + 64 * k];
  }
  const float b_o  = a.sa_out_b[gw];
  const float b_1a = a.ff1_b[2 * gw];
  const float b_1b = a.ff1_b[2 * gw + 1];
  const float b_2  = a.ff2_b[gw];
  const float b_vr = a.vr_b[gw];

  float c0 = 0.f, c1 = 0.f, c2 = 0.f, c3 = 0.f;
  float xres = a.obj_w[(size_t)gw * 80] + ldc(a.peT + gw);
  float vrr[16], cmr[16];

  for (int i = 0; i < SEQ; ++i){
    // ---- MS2: attention -> u
    {
      float vv[4], qq[4];
      poll8x(a.vcB + (size_t)i * DIM + tid, a.qv + (size_t)i * DIM + tid, 256, vv, qq);
      smB[tid] = vv[0]; smB[tid + 256] = vv[1]; smB[tid + 512] = vv[2]; smB[tid + 768] = vv[3];
      smC[tid] = qq[0]; smC[tid + 256] = qq[1]; smC[tid + 512] = qq[2]; smC[tid + 768] = qq[3];
      __syncthreads();
      // c-update from V row
      float p0 = 0.f, p1 = 0.f, p2 = 0.f, p3 = 0.f;
      #pragma unroll
      for (int k = 0; k < 4; ++k){
        p0 = fmaf(wo[k],      smB[lane + 64 * k],        p0);
        p1 = fmaf(wo[k + 4],  smB[lane + 64 * (k + 4)],  p1);
        p2 = fmaf(wo[k + 8],  smB[lane + 64 * (k + 8)],  p2);
        p3 = fmaf(wo[k + 12], smB[lane + 64 * (k + 12)], p3);
      }
      p0 = wsum(p0); p1 = wsum(p1); p2 = wsum(p2); p3 = wsum(p3);
      if (lane == i){ c0 = p0; c1 = p1; c2 = p2; c3 = p3; }
      // scores: wave handles j = wave (mod 4).  Rows j<i: PLAIN loads (their
      // stores were vmcnt-drained at iteration j-1's stage end, long before the
      // vcB[i] stores we just detected -> guaranteed visible).  Software-
      // pipelined 2-deep so LLC latency overlaps compute.  Row j==i: sentinel
      // poll (same-stage store as vcB[i], no ordering guarantee).
      {
        float kv0[8], kv1[8], kn0[8], kn1[8];
        int j = wave;
        if (j < i){
          const float* kr = a.kc + (size_t)j * DIM + lane;
          #pragma unroll
          for (int m = 0; m < 8; ++m){ kv0[m] = ldc(kr + 64 * m); kv1[m] = ldc(kr + 512 + 64 * m); }
        }
        for (; j < i; j += 4){
          int jn = j + 4;
          if (jn < i){
            const float* krn = a.kc + (size_t)jn * DIM + lane;
            #pragma unroll
            for (int m = 0; m < 8; ++m){ kn0[m] = ldc(krn + 64 * m); kn1[m] = ldc(krn + 512 + 64 * m); }
          }
          float s0 = 0.f, s1 = 0.f, s2 = 0.f, s3 = 0.f;
          #pragma unroll
          for (int m = 0; m < 4; ++m){
            s0 = fmaf(smC[lane + 64 * m],       kv0[m],     s0);
            s1 = fmaf(smC[256 + lane + 64 * m], kv0[4 + m], s1);
            s2 = fmaf(smC[512 + lane + 64 * m], kv1[m],     s2);
            s3 = fmaf(smC[768 + lane + 64 * m], kv1[4 + m], s3);
          }
          s0 = wsum(s0); s1 = wsum(s1); s2 = wsum(s2); s3 = wsum(s3);
          if (lane == 0){
            float ab = (float)((i - j) / 30);
            scp[j]       = s0 * 0.0625f - 0.25f       * ab;
            scp[64 + j]  = s1 * 0.0625f - 0.0625f     * ab;
            scp[128 + j] = s2 * 0.0625f - 0.015625f   * ab;
            scp[192 + j] = s3 * 0.0625f - 0.00390625f * ab;
          }
          if (jn < i){
            #pragma unroll
            for (int m = 0; m < 8; ++m){ kv0[m] = kn0[m]; kv1[m] = kn1[m]; }
          }
        }
        if ((i & 3) == wave){
          const float* kr = a.kc + (size_t)i * DIM + lane;
          float kva[8], kvb[8];
          poll8s(kr, kva);
          poll8s(kr + 512, kvb);
          float s0 = 0.f, s1 = 0.f, s2 = 0.f, s3 = 0.f;
          #pragma unroll
          for (int m = 0; m < 4; ++m){
            s0 = fmaf(smC[lane + 64 * m],       kva[m],     s0);
            s1 = fmaf(smC[256 + lane + 64 * m], kva[4 + m], s1);
            s2 = fmaf(smC[512 + lane + 64 * m], kvb[m],     s2);
            s3 = fmaf(smC[768 + lane + 64 * m], kvb[4 + m], s3);
          }
          s0 = wsum(s0); s1 = wsum(s1); s2 = wsum(s2); s3 = wsum(s3);
          if (lane == 0){   // alibi term is 0 for j == i
            scp[i]       = s0 * 0.0625f;
            scp[64 + i]  = s1 * 0.0625f;
            scp[128 + i] = s2 * 0.0625f;
            scp[192 + i] = s3 * 0.0625f;
          }
        }
      }
      __syncthreads();
      // softmax: wave = head
      {
        float sv = (lane <= i) ? scp[wave * 64 + lane] : -3.0e38f;
        float mx = wmax(sv);
        float p = (lane <= i) ? __expf(sv - mx) : 0.f;
        float sum = wsum(p);
        scp[wave * 64 + lane] = p / sum;
      }
      __syncthreads();
      float t = scp[lane] * c0 + scp[64 + lane] * c1 + scp[128 + lane] * c2 + scp[192 + lane] * c3;
      t = wsum(t);
      if (lane == 0) stc(a.uB + (size_t)i * DIM + gw, xres + t + b_o);
      __syncthreads();
    }

    // ---- MS3: ln1 -> +cac -> ln2 ; ff1 -> hb
    float x2v;
    {
      float cr[4];
      #pragma unroll
      for (int k = 0; k < 4; ++k) cr[k] = ldc(a.cac + (size_t)i * DIM + tid + 256 * k);
      float uv[4];
      poll4s(a.uB + (size_t)i * DIM + tid, 256, uv);
      smA[tid] = uv[0]; smA[tid + 256] = uv[1]; smA[tid + 512] = uv[2]; smA[tid + 768] = uv[3];
      __syncthreads();
      float sa = 0.f, sb = 0.f;
      #pragma unroll
      for (int k = 0; k < 4; ++k){ float x = smA[tid + 256 * k]; sa += x; sb = fmaf(x, x, sb); }
      float2 r = breduce2(sa, sb, red);
      float mean = r.x * (1.f / 1024.f);
      float var  = r.y * (1.f / 1024.f) - mean * mean;
      float rs = 1.f / sqrtf(var + 1e-5f);
      float tv[4];
      float ta = 0.f, tb = 0.f;
      #pragma unroll
      for (int k = 0; k < 4; ++k){
        int d = tid + 256 * k;
        float x1 = (smA[d] - mean) * rs * a.ln1_g[d] + a.ln1_b[d];
        tv[k] = x1 + cr[k];
        ta += tv[k]; tb = fmaf(tv[k], tv[k], tb);
      }
      float2 r2v = breduce2(ta, tb, red);
      float mean2 = r2v.x * (1.f / 1024.f);
      float var2  = r2v.y * (1.f / 1024.f) - mean2 * mean2;
      float rs2 = 1.f / sqrtf(var2 + 1e-5f);
      #pragma unroll
      for (int k = 0; k < 4; ++k){
        int d = tid + 256 * k;
        smA[d] = (tv[k] - mean2) * rs2 * a.ln2_g[d] + a.ln2_b[d];
      }
      __syncthreads();
      x2v = smA[gw];
      float acc0 = 0.f, acc1 = 0.f;
      #pragma unroll
      for (int k = 0; k < 16; ++k){
        float x = smA[lane + 64 * k];
        acc0 = fmaf(f1a[k], x, acc0);
        acc1 = fmaf(f1b[k], x, acc1);
      }
      acc0 = wsum(acc0); acc1 = wsum(acc1);
      if (lane == 0){
        stc(a.hbB + (size_t)i * 2048 + 2 * gw,     fmaxf(acc0 + b_1a, 0.f));
        stc(a.hbB + (size_t)i * 2048 + 2 * gw + 1, fmaxf(acc1 + b_1b, 0.f));
      }
      __syncthreads();
    }

    // ---- MS4: ff2 -> w ; prefetch vr_w/Cm rows
    {
      const float* pr = a.vr_w + (size_t)gw * DIM;
      const float* pc = a.Cm + (size_t)gw * DIM;
      #pragma unroll
      for (int k = 0; k < 16; ++k){ vrr[k] = pr[lane + 64 * k]; cmr[k] = pc[lane + 64 * k]; }
      float h0[4], h1[4];
      poll8x(a.hbB + (size_t)i * 2048 + tid, a.hbB + (size_t)i * 2048 + 1024 + tid, 256, h0, h1);
      #pragma unroll
      for (int k = 0; k < 4; ++k){ smA[tid + 256 * k] = h0[k]; smA[tid + 1024 + 256 * k] = h1[k]; }
      __syncthreads();
      float acc = 0.f;
      #pragma unroll
      for (int k = 0; k < 32; ++k) acc = fmaf(f2[k], smA[lane + 64 * k], acc);
      acc = wsum(acc);
      if (lane == 0) stc(a.wB + (size_t)i * DIM + gw, x2v + acc + b_2);
      __syncthreads();
    }

    // ---- MS1': ln3 -> y ; out row i ; folded QKV + residual for i+1
    {
      float wv4[4];
      poll4s(a.wB + (size_t)i * DIM + tid, 256, wv4);
      smA[tid] = wv4[0]; smA[tid + 256] = wv4[1]; smA[tid + 512] = wv4[2]; smA[tid + 768] = wv4[3];
      __syncthreads();
      float sa = 0.f, sb = 0.f;
      #pragma unroll
      for (int k = 0; k < 4; ++k){ float x = smA[tid + 256 * k]; sa += x; sb = fmaf(x, x, sb); }
      float2 r = breduce2(sa, sb, red);
      float mean = r.x * (1.f / 1024.f);
      float var  = r.y * (1.f / 1024.f) - mean * mean;
      float rs = 1.f / sqrtf(var + 1e-5f);
      float ov[4];
      #pragma unroll
      for (int k = 0; k < 4; ++k){
        int d = tid + 256 * k;
        ov[k] = (smA[d] - mean) * rs * a.ln3_g[d] + a.ln3_b[d];
      }
      __syncthreads();
      #pragma unroll
      for (int k = 0; k < 4; ++k) smA[tid + 256 * k] = ov[k];
      __syncthreads();
      float ar = 0.f, ac = 0.f, aqn = 0.f, akn = 0.f, avn = 0.f;
      #pragma unroll
      for (int k = 0; k < 16; ++k){
        float x = smA[lane + 64 * k];
        ar  = fmaf(vrr[k], x, ar);
        ac  = fmaf(cmr[k], x, ac);
        aqn = fmaf(fq[k], x, aqn);
        akn = fmaf(fk[k], x, akn);
        avn = fmaf(fv[k], x, avn);
      }
      ar = wsum(ar); ac = wsum(ac);
      aqn = wsum(aqn); akn = wsum(akn); avn = wsum(avn);
      if (lane == 0) a.out[(size_t)i * DIM + gw] = ar + b_vr;
      if (i < SEQ - 1){
        int pn = (i + 1) % 30;
        if (lane == 0){
          float tq = ldc(a.wqpeT + (size_t)pn * DIM + gw);
          float tk = ldc(a.wkpeT + (size_t)pn * DIM + gw);
          float tv = ldc(a.wvpeT + (size_t)pn * DIM + gw);
          stc(a.qv + (size_t)(i + 1) * DIM + gw, aqn + aqcb + tq);
          stc(a.kc + (size_t)(i + 1) * DIM + gw, akn + akcb + tk);
          stc(a.vcB + (size_t)(i + 1) * DIM + gw, avn + avcb + tv);
        }
        xres = ac + cbv + ldc(a.peT + (size_t)pn * DIM + gw);
      }
      __syncthreads();
    }
  }
}

// ---------------- host launcher ----------------
extern "C" void kernel_launch(void* const* d_in, const int* in_sizes, int n_in,
                              void* d_out, int out_size, void* d_ws, size_t ws_size,
                              hipStream_t stream){
  const float* hs       = (const float*)d_in[0];
  const float* hid_w    = (const float*)d_in[1];
  const float* hid_b    = (const float*)d_in[2];
  const float* obj_w    = (const float*)d_in[3];
  const float* sa_in_w  = (const float*)d_in[4];
  const float* sa_in_b  = (const float*)d_in[5];
  const float* sa_out_w = (const float*)d_in[6];
  const float* sa_out_b = (const float*)d_in[7];
  const float* ca_in_w  = (const float*)d_in[8];
  const float* ca_in_b  = (const float*)d_in[9];
  const float* ca_out_w = (const float*)d_in[10];
  const float* ca_out_b = (const float*)d_in[11];
  const float* ln1_g    = (const float*)d_in[12];
  const float* ln1_b    = (const float*)d_in[13];
  const float* ln2_g    = (const float*)d_in[14];
  const float* ln2_b    = (const float*)d_in[15];
  const float* ln3_g    = (const float*)d_in[16];
  const float* ln3_b    = (const float*)d_in[17];
  const float* ff1_w    = (const float*)d_in[18];
  const float* ff1_b    = (const float*)d_in[19];
  const float* ff2_w    = (const float*)d_in[20];
  const float* ff2_b    = (const float*)d_in[21];
  const float* vr_w     = (const float*)d_in[22];
  const float* vr_b     = (const float*)d_in[23];
  const float* vm_w     = (const float*)d_in[24];
  const float* vm_b     = (const float*)d_in[25];

  float* ws = (float*)d_ws;
  float* mem    = ws;                 // 65536
  float* vtmp   = ws + 65536;         // 65536
  float* cac    = ws + 131072;        // 65536
  // ---- write-once dataflow region (sentinel-initialized each launch) ----
  float* kc     = ws + 196608;        // 65536  [64][1024]
  float* qv     = ws + 262144;        // 65536
  float* vcB    = ws + 327680;        // 65536
  float* uB     = ws + 393216;        // 65536
  float* hbB    = ws + 458752;        // 131072 [64][2048]
  float* wB     = ws + 589824;        // 65536
  // ---- constants / tables ----
  float* peT    = ws + 655360;        // 30720
  float* stylev = ws + 686080;        // 1024
  float* cbvec  = ws + 687104;        // 1024
  float* wqpeT  = ws + 688128;        // 30720
  float* wkpeT  = ws + 718848;        // 30720
  float* wvpeT  = ws + 749568;        // 30720
  unsigned* bar = (unsigned*)(ws + 780288);   // 256 lines x 128B = 32KB
  float* Cm     = ws + 788480;        // 1048576
  float* WqF    = ws + 1837056;       // 1048576
  float* WkF    = ws + 2885632;       // 1048576
  float* WvF    = ws + 3934208;       // 1048576 -> end 4982784 floats (~20MB)

  hipMemsetAsync((void*)bar, 0, 256 * SLOT_STRIDE * 4, stream);
  sentinit<<<512, 256, 0, stream>>>((unsigned*)kc, 458752);   // kc..wB

  mm1024<<<dim3(16, 16, 1), 256, 0, stream>>>(vm_w, vr_w, Cm, 0, 0);
  mm1024<<<dim3(16, 16, 3), 256, 0, stream>>>(sa_in_w, Cm, WqF,
                                              (size_t)1024 * 1024, (size_t)1024 * 1024);

  CoopArgs A;
  A.hs = hs; A.hid_w = hid_w; A.hid_b = hid_b;
  A.sa_in_w = sa_in_w; A.sa_in_b = sa_in_b; A.sa_out_w = sa_out_w; A.sa_out_b = sa_out_b;
  A.ca_in_w = ca_in_w; A.ca_in_b = ca_in_b; A.ca_out_w = ca_out_w; A.ca_out_b = ca_out_b;
  A.ln1_g = ln1_g; A.ln1_b = ln1_b; A.ln2_g = ln2_g; A.ln2_b = ln2_b; A.ln3_g = ln3_g; A.ln3_b = ln3_b;
  A.ff1_w = ff1_w; A.ff1_b = ff1_b; A.ff2_w = ff2_w; A.ff2_b = ff2_b;
  A.vr_w = vr_w; A.vr_b = vr_b; A.vm_w = vm_w; A.vm_b = vm_b; A.obj_w = obj_w;
  A.Cm = Cm; A.WqF = WqF; A.WkF = WkF; A.WvF = WvF;
  A.mem = mem; A.vtmp = vtmp; A.cac = cac;
  A.kc = kc; A.qv = qv; A.vcB = vcB; A.uB = uB; A.hbB = hbB; A.wB = wB;
  A.peT = peT; A.stylev = stylev; A.cbvec = cbvec;
  A.wqpeT = wqpeT; A.wkpeT = wkpeT; A.wvpeT = wvpeT;
  A.out = (float*)d_out;
  A.bar = bar;

  void* params[1] = { &A };
  hipError_t e = hipLaunchCooperativeKernel((void*)decode_loop, dim3(NBLK), dim3(TPB), params, 0, stream);
  if (e != hipSuccess){
    decode_loop<<<dim3(NBLK), dim3(TPB), 0, stream>>>(A);
  }
}